// Round 15
// baseline (1972.363 us; speedup 1.0000x reference)
//
#include <hip/hip_runtime.h>

#define B_   1024
#define T_   512
#define I_   16
#define H_   50
#define FC_  64
#define W0S  52     // W0H row: 50 h-weights + 2 ZERO pad (52%32=20 -> balanced banks)
#define W1S  100    // W1 row: 50 ih | 50 hh               (100%32=4 -> balanced banks)
#define HBS  100    // per-row h buffer: [0..49]=h0, [50..99]=h1
#define RW   2      // batch rows per wave (one weight read feeds both rows' FMAs)
#define NW   2      // waves per block

typedef float v2f __attribute__((ext_vector_type(2)));

__device__ __forceinline__ float frcp(float x)   { return __builtin_amdgcn_rcpf(x); }
__device__ __forceinline__ float sigm(float x)   { return frcp(1.f + __expf(-x)); }
__device__ __forceinline__ float tanh_f(float x) { return 1.f - 2.f * frcp(1.f + __expf(2.f * x)); }
__device__ __forceinline__ v2f   mk2(float a, float b) { v2f r; r.x = a; r.y = b; return r; }
__device__ __forceinline__ v2f   xy(float4 v) { return mk2(v.x, v.y); }
__device__ __forceinline__ v2f   zw(float4 v) { return mk2(v.z, v.w); }

// packed fp32 FMA (one VOP3P instr; halves the dominant FMA stream)
__device__ __forceinline__ v2f pk_fma(v2f a, v2f b, v2f acc) {
    asm("v_pk_fma_f32 %0, %1, %2, %0" : "+v"(acc) : "v"(a), "v"(b));
    return acc;
}

// WAVE-AUTONOMOUS LSTM, 2 rows/lane: one wave = 2 batch rows, both layers;
// lane u (<50) owns ALL 4 gates of unit u (full dots in-lane: no cross-lane
// joins, no gate exchange). h-weights in LDS (120.3 KiB total, staged once,
// shared by 2 waves); x-weights in VGPRs (64/lane); h in per-row LDS buffers.
// ZERO __syncthreads() in the T-loop: same-wave LDS write->read ordering via
// s_waitcnt lgkmcnt(0) (2/step). The barrier convoy that floored structure A
// (R2..R13) at ~2400-5000 cyc/step is gone. Each weight ds_read feeds BOTH
// rows' FMAs -> LDS stream per CU-step ~= 2 waves x 122KB -> ~2400 bank-cyc.
__global__ __launch_bounds__(128, 1) void lstm_wave2(
    const float* __restrict__ x,
    const float* __restrict__ w_ih0, const float* __restrict__ w_hh0,
    const float* __restrict__ b_ih0, const float* __restrict__ b_hh0,
    const float* __restrict__ w_ih1, const float* __restrict__ w_hh1,
    const float* __restrict__ b_ih1, const float* __restrict__ b_hh1,
    const float* __restrict__ fc1_w, const float* __restrict__ fc1_b,
    const float* __restrict__ fc2_w, const float* __restrict__ fc2_b,
    float* __restrict__ out)
{
    __shared__ float W0H[200 * W0S];        // 41.6 KB  (layer-0 h-weights, zero-padded)
    __shared__ float W1 [200 * W1S];        // 80.0 KB  (layer-1 ih|hh)
    __shared__ float hbuf[NW * RW][HBS];    // 1.6 KB   (total 123.2 KB -> 1 block/CU)

    const int tid   = threadIdx.x;
    const int wv    = tid >> 6;
    const int ln    = tid & 63;
    const int u     = (ln < H_) ? ln : (H_ - 1);   // clamp for reads; writes masked
    const bool wr   = (ln < H_);
    const int rbase = blockIdx.x * (NW * RW) + wv * RW;

    // ---- stage LDS weights (once) ----
    for (int g = tid; g < 4 * H_; g += 128) {
        float* d0 = W0H + g * W0S;
        #pragma unroll 2
        for (int k = 0; k < H_; ++k) d0[k] = w_hh0[g * H_ + k];
        d0[50] = 0.f; d0[51] = 0.f;
        float* d1 = W1 + g * W1S;
        #pragma unroll 2
        for (int k = 0; k < H_; ++k) {
            d1[k]      = w_ih1[g * H_ + k];
            d1[H_ + k] = w_hh1[g * H_ + k];
        }
    }
    for (int i = tid; i < NW * RW * HBS; i += 128) ((float*)hbuf)[i] = 0.f;
    __syncthreads();                        // the ONLY block barrier

    // ---- per-lane gate rows: pointers, biases, x-weights in registers ----
    const float* w0r[4]; const float* w1r[4];
    float b0[4], b1[4];
    v2f w0x[4][8];                          // 64 VGPRs of layer-0 x-weights
    #pragma unroll
    for (int j = 0; j < 4; ++j) {
        const int g = j * H_ + u;
        w0r[j] = W0H + g * W0S;
        w1r[j] = W1  + g * W1S;
        b0[j]  = b_ih0[g] + b_hh0[g];
        b1[j]  = b_ih1[g] + b_hh1[g];
        #pragma unroll
        for (int k = 0; k < 8; ++k)
            w0x[j][k] = mk2(w_ih0[g * I_ + 2 * k], w_ih0[g * I_ + 2 * k + 1]);
    }
    float* hb[RW];
    const float* xr[RW];
    #pragma unroll
    for (int r = 0; r < RW; ++r) {
        hb[r] = hbuf[wv * RW + r];
        xr[r] = x + (size_t)(rbase + r) * T_ * I_;
    }
    float c0[RW] = {0.f, 0.f}, c1[RW] = {0.f, 0.f};

    for (int t = 0; t < T_; ++t) {
        // x(t): issue early, consume after the 52 LDS weight reads (latency hidden)
        float4 xv[RW][4];
        #pragma unroll
        for (int r = 0; r < RW; ++r)
            #pragma unroll
            for (int q = 0; q < 4; ++q)
                xv[r][q] = *(const float4*)(xr[r] + t * I_ + q * 4);

        // ---- L0: dot over h0(t-1) (LDS weights, shared read) + x(t) (reg weights) ----
        v2f A[RW][4];
        #pragma unroll
        for (int r = 0; r < RW; ++r)
            #pragma unroll
            for (int j = 0; j < 4; ++j) A[r][j] = mk2(0.f, 0.f);

        #pragma unroll
        for (int k = 0; k < 13; ++k) {      // 4 weight reads feed 16 pk_fma (2 rows)
            float4 w[4];
            #pragma unroll
            for (int j = 0; j < 4; ++j) w[j] = *(const float4*)(w0r[j] + k * 4);
            const float4 o0 = *(const float4*)(hb[0] + k * 4);
            const float4 o1 = *(const float4*)(hb[1] + k * 4);
            #pragma unroll
            for (int j = 0; j < 4; ++j) {
                A[0][j] = pk_fma(xy(w[j]), xy(o0), A[0][j]);
                A[0][j] = pk_fma(zw(w[j]), zw(o0), A[0][j]);
                A[1][j] = pk_fma(xy(w[j]), xy(o1), A[1][j]);
                A[1][j] = pk_fma(zw(w[j]), zw(o1), A[1][j]);
            }
        }
        #pragma unroll
        for (int r = 0; r < RW; ++r) {      // x part: weights already in VGPRs
            #pragma unroll
            for (int j = 0; j < 4; ++j) {
                #pragma unroll
                for (int q = 0; q < 4; ++q) {
                    A[r][j] = pk_fma(w0x[j][2 * q],     xy(xv[r][q]), A[r][j]);
                    A[r][j] = pk_fma(w0x[j][2 * q + 1], zw(xv[r][q]), A[r][j]);
                }
            }
            const float ai = A[r][0].x + A[r][0].y + b0[0];
            const float af = A[r][1].x + A[r][1].y + b0[1];
            const float ag = A[r][2].x + A[r][2].y + b0[2];
            const float ao = A[r][3].x + A[r][3].y + b0[3];
            const float gi = sigm(ai), gf = sigm(af), gg = tanh_f(ag), go = sigm(ao);
            c0[r] = fmaf(gf, c0[r], gi * gg);
            const float h0v = go * tanh_f(c0[r]);
            if (wr) hb[r][u] = h0v;         // overwrite h0 (old h0 reads all done)
        }
        asm volatile("s_waitcnt lgkmcnt(0)" ::: "memory");   // h0(t) visible wave-wide

        // ---- L1: dot over [h0(t) | h1(t-1)] (contiguous 100 floats) ----
        v2f Bq[RW][4];
        #pragma unroll
        for (int r = 0; r < RW; ++r)
            #pragma unroll
            for (int j = 0; j < 4; ++j) Bq[r][j] = mk2(0.f, 0.f);

        #pragma unroll
        for (int k = 0; k < 25; ++k) {
            float4 w[4];
            #pragma unroll
            for (int j = 0; j < 4; ++j) w[j] = *(const float4*)(w1r[j] + k * 4);
            const float4 o0 = *(const float4*)(hb[0] + k * 4);
            const float4 o1 = *(const float4*)(hb[1] + k * 4);
            #pragma unroll
            for (int j = 0; j < 4; ++j) {
                Bq[0][j] = pk_fma(xy(w[j]), xy(o0), Bq[0][j]);
                Bq[0][j] = pk_fma(zw(w[j]), zw(o0), Bq[0][j]);
                Bq[1][j] = pk_fma(xy(w[j]), xy(o1), Bq[1][j]);
                Bq[1][j] = pk_fma(zw(w[j]), zw(o1), Bq[1][j]);
            }
        }
        #pragma unroll
        for (int r = 0; r < RW; ++r) {
            const float ai = Bq[r][0].x + Bq[r][0].y + b1[0];
            const float af = Bq[r][1].x + Bq[r][1].y + b1[1];
            const float ag = Bq[r][2].x + Bq[r][2].y + b1[2];
            const float ao = Bq[r][3].x + Bq[r][3].y + b1[3];
            const float gi = sigm(ai), gf = sigm(af), gg = tanh_f(ag), go = sigm(ao);
            c1[r] = fmaf(gf, c1[r], gi * gg);
            const float h1v = go * tanh_f(c1[r]);
            if (wr) hb[r][H_ + u] = h1v;    // h1(t) (h1(t-1) reads all done)
        }
        asm volatile("s_waitcnt lgkmcnt(0)" ::: "memory");   // h1(t) visible wave-wide
    }

    // ---- FC epilogue: per wave, lane f = fc1 row f; shuffle-reduce per row ----
    #pragma unroll
    for (int r = 0; r < RW; ++r) {
        float a = fc1_b[ln];
        #pragma unroll 2
        for (int j = 0; j < H_; ++j)
            a = fmaf(fc1_w[ln * H_ + j], hb[r][H_ + j], a);
        float v = fmaxf(a, 0.f) * fc2_w[ln];
        #pragma unroll
        for (int off = 1; off < FC_; off <<= 1) v += __shfl_xor(v, off);
        if (ln == 0) out[rbase + r] = v + fc2_b[0];
    }
}

extern "C" void kernel_launch(void* const* d_in, const int* in_sizes, int n_in,
                              void* d_out, int out_size, void* d_ws, size_t ws_size,
                              hipStream_t stream) {
    const float* x     = (const float*)d_in[0];
    const float* w_ih0 = (const float*)d_in[1];
    const float* w_hh0 = (const float*)d_in[2];
    const float* b_ih0 = (const float*)d_in[3];
    const float* b_hh0 = (const float*)d_in[4];
    const float* w_ih1 = (const float*)d_in[5];
    const float* w_hh1 = (const float*)d_in[6];
    const float* b_ih1 = (const float*)d_in[7];
    const float* b_hh1 = (const float*)d_in[8];
    const float* fc1_w = (const float*)d_in[9];
    const float* fc1_b = (const float*)d_in[10];
    const float* fc2_w = (const float*)d_in[11];
    const float* fc2_b = (const float*)d_in[12];
    float* out = (float*)d_out;

    dim3 grid(B_ / (NW * RW)), block(NW * 64);
    hipLaunchKernelGGL(lstm_wave2, grid, block, 0, stream,
                       x, w_ih0, w_hh0, b_ih0, b_hh0,
                       w_ih1, w_hh1, b_ih1, b_hh1,
                       fc1_w, fc1_b, fc2_w, fc2_b, out);
}

// Round 16
// 1017.086 us; speedup vs baseline: 1.9392x; 1.9392x over previous
//
#include <hip/hip_runtime.h>

#define B_    1024
#define T_    512
#define I_    16
#define H_    50
#define FC_   64
#define HALFW 28    // half of padded H (56)
#define HP    56    // H padded for float4 reads
#define R_    4     // batch rows per block

typedef float v2f __attribute__((ext_vector_type(2)));

__device__ __forceinline__ float frcp(float x)   { return __builtin_amdgcn_rcpf(x); }
__device__ __forceinline__ float sigm(float x)   { return frcp(1.0f + __expf(-x)); }
__device__ __forceinline__ float tanh_f(float x) { return 1.0f - 2.0f * frcp(1.0f + __expf(2.0f * x)); }
__device__ __forceinline__ v2f   mk2(float a, float b) { v2f r; r.x = a; r.y = b; return r; }

// forced packed fp32 FMA (one VOP3P instr)
__device__ __forceinline__ v2f pk_fma(v2f a, v2f b, v2f acc) {
    asm("v_pk_fma_f32 %0, %1, %2, %0" : "+v"(acc) : "v"(a), "v"(b));
    return acc;
}

// intra-quad shuffles on the VALU (DPP quad_perm)
__device__ __forceinline__ float dpp_xor1(float v) {   // swap (0,1),(2,3)
    return __int_as_float(__builtin_amdgcn_update_dpp(0, __float_as_int(v), 0xB1, 0xF, 0xF, true));
}
__device__ __forceinline__ float dpp_xor2(float v) {   // swap (0,2),(1,3)
    return __int_as_float(__builtin_amdgcn_update_dpp(0, __float_as_int(v), 0x4E, 0xF, 0xF, true));
}

#define PKDOT(acc, W, kk, hv) { acc = pk_fma(W[2*(kk)],   mk2(hv.x, hv.y), acc); \
                                acc = pk_fma(W[2*(kk)+1], mk2(hv.z, hv.w), acc); }
#define XDOT(acc, Wj, v0, v1) { acc = pk_fma(Wj[0], mk2(v0.x, v0.y), acc); \
                                acc = pk_fma(Wj[1], mk2(v0.z, v0.w), acc); \
                                acc = pk_fma(Wj[2], mk2(v1.x, v1.y), acc); \
                                acc = pk_fma(Wj[3], mk2(v1.z, v1.w), acc); }

// LAYER-PIPELINED (R11 clean base: VGPR=128, WRITE=8KB, 4 rows/CU) +
//  1. x staged into an LDS ring by team-1 wave 0 with a distance-2 register
//     pipeline: load x(t+2)->reg at iter t, ds_write at iter t+1 (vmcnt is
//     drained by the intervening barrier -> ZERO stall); removes the exposed
//     x global-load latency (x working set = 4MB/XCD, exactly at L2 capacity)
//     and ~60 live registers from team 0's phase.
//  2. s_setprio(1) around each team's dot+cell (teams are phase-skewed ->
//     scheduler arbitration pays, per T5's role-split condition).
//  3. pk_fma inline asm; single-pass r-loop (acc transient).
__global__ __launch_bounds__(512) __attribute__((amdgpu_waves_per_eu(2, 2)))
void lstm_pipe4(
    const float* __restrict__ x,
    const float* __restrict__ w_ih0, const float* __restrict__ w_hh0,
    const float* __restrict__ b_ih0, const float* __restrict__ b_hh0,
    const float* __restrict__ w_ih1, const float* __restrict__ w_hh1,
    const float* __restrict__ b_ih1, const float* __restrict__ b_hh1,
    const float* __restrict__ fc1_w, const float* __restrict__ fc1_b,
    const float* __restrict__ fc2_w, const float* __restrict__ fc2_b,
    float* __restrict__ out)
{
    __shared__ float h0s[2][R_][HP];     // [pingpong][row][HP]
    __shared__ float h1s[2][R_][HP];
    __shared__ float xs[4][R_ * I_];     // x ring: slot t&3 holds x(:, t, :)

    const int tid  = threadIdx.x;
    const int team = tid >> 8;          // 0: layer 0, 1: layer 1
    const int lt   = tid & 255;
    const int u    = lt >> 2;
    const int qp   = (lt >> 1) & 1;
    const int s    = lt & 1;
    const bool gl  = lt < 4 * H_;       // 200 working lanes per team
    const int row0 = blockIdx.x * R_;

    // activation selectors for gate j=0 (qp0 -> i: sigmoid, qp1 -> g: tanh)
    const float qa = qp ? 2.0f : -1.0f;
    const float qb = qp ? 1.0f :  0.0f;
    const float qm = qp ? -2.0f : 1.0f;

    // ---- per-team weight registers (aliased): team0 72, team1 112 regs ----
    v2f wX[2][14], wY[2][14];
    float bias[2] = {0.f, 0.f};
    if (gl) {
        #pragma unroll
        for (int j = 0; j < 2; ++j) {
            const int g = (2 * qp + j) * H_ + u;
            if (team == 0) {
                #pragma unroll
                for (int k = 0; k < 14; ++k) {
                    const int j0 = s * HALFW + 2 * k, j1 = j0 + 1;
                    wX[j][k] = mk2(j0 < H_ ? w_hh0[g * H_ + j0] : 0.f,
                                   j1 < H_ ? w_hh0[g * H_ + j1] : 0.f);
                }
                #pragma unroll
                for (int k = 0; k < 4; ++k)
                    wY[j][k] = mk2(w_ih0[g * I_ + s * 8 + 2 * k],
                                   w_ih0[g * I_ + s * 8 + 2 * k + 1]);
                if (s == 0) bias[j] = b_ih0[g] + b_hh0[g];
            } else {
                #pragma unroll
                for (int k = 0; k < 14; ++k) {
                    const int j0 = s * HALFW + 2 * k, j1 = j0 + 1;
                    wX[j][k] = mk2(j0 < H_ ? w_ih1[g * H_ + j0] : 0.f,
                                   j1 < H_ ? w_ih1[g * H_ + j1] : 0.f);
                    wY[j][k] = mk2(j0 < H_ ? w_hh1[g * H_ + j0] : 0.f,
                                   j1 < H_ ? w_hh1[g * H_ + j1] : 0.f);
                }
                if (s == 0) bias[j] = b_ih1[g] + b_hh1[g];
            }
        }
    }

    if (tid < 2 * R_ * HP) { ((float*)h0s)[tid] = 0.f; ((float*)h1s)[tid] = 0.f; }

    // ---- x staging prologue (team-1 wave 0; lane l covers row l>>4, elem l&15) ----
    const bool stg = (team == 1) && (lt < R_ * I_);
    const float* sbase = nullptr;
    float x_pend = 0.f;                 // x(t+2) in flight
    if (stg) {
        sbase = x + (size_t)(row0 + (lt >> 4)) * T_ * I_ + (lt & 15);
        xs[0][lt] = sbase[0];           // x(0) -> slot 0 (waitcnt inserted here)
        x_pend = sbase[(size_t)1 * I_]; // x(1) pending, written at t=0
    }
    float c[R_] = {0.f, 0.f, 0.f, 0.f};
    __syncthreads();

    auto cell = [&](v2f P0, v2f P1, float& cc) -> float {
        float p0 = P0.x + P0.y;  p0 += dpp_xor1(p0);
        float p1 = P1.x + P1.y;  p1 += dpp_xor1(p1);
        float act0 = qb + qm * frcp(1.0f + __expf(qa * p0));  // i (qp0) or g (qp1)
        float act1 = sigm(p1);                                // f (qp0) or o (qp1)
        float ox0 = dpp_xor2(act0);
        float ox1 = dpp_xor2(act1);
        float gi = qp ? ox0 : act0;
        float gf = qp ? ox1 : act1;
        float gg = qp ? act0 : ox0;
        float go = qp ? act1 : ox1;
        cc = gf * cc + gi * gg;
        return go * tanh_f(cc);
    };

    // ---- main loop: L0 computes h0(t); L1 computes h1(t-1). One barrier. ----
    #pragma unroll 2
    for (int t = 0; t < T_; ++t) {
        const int pp = t & 1;
        // stage: write x(t+1) (loaded last iter; vmcnt drained by barrier),
        // then issue load of x(t+2) -> zero exposed latency anywhere.
        if (stg) {
            xs[(t + 1) & 3][lt] = x_pend;
            const int ts = (t + 2 < T_) ? (t + 2) : (T_ - 1);
            x_pend = sbase[(size_t)ts * I_];
        }
        if (team == 0) {
            if (gl) {
                __builtin_amdgcn_s_setprio(1);
                #pragma unroll
                for (int r = 0; r < R_; ++r) {
                    const float4* hp = (const float4*)(&h0s[pp][r][s * HALFW]);
                    const float4* xp = (const float4*)(&xs[t & 3][r * I_ + s * 8]);
                    v2f P0 = mk2(bias[0], 0.f), P1 = mk2(bias[1], 0.f);
                    const float4 xv0 = xp[0], xv1 = xp[1];
                    #pragma unroll
                    for (int k = 0; k < 7; ++k) {
                        float4 hv = hp[k];
                        PKDOT(P0, wX[0], k, hv); PKDOT(P1, wX[1], k, hv);
                    }
                    XDOT(P0, wY[0], xv0, xv1);
                    XDOT(P1, wY[1], xv0, xv1);
                    float hv = cell(P0, P1, c[r]);
                    if ((lt & 3) == 0) h0s[pp ^ 1][r][u] = hv;
                }
                __builtin_amdgcn_s_setprio(0);
            }
        } else {
            if (gl && t > 0) {                       // L1 lags by one step
                __builtin_amdgcn_s_setprio(1);
                #pragma unroll
                for (int r = 0; r < R_; ++r) {
                    const float4* h0p = (const float4*)(&h0s[pp][r][s * HALFW]);  // h0(t-1)
                    const float4* h1p = (const float4*)(&h1s[pp][r][s * HALFW]);  // h1(t-2)
                    v2f P0 = mk2(bias[0], 0.f), P1 = mk2(bias[1], 0.f);
                    #pragma unroll
                    for (int k = 0; k < 7; ++k) {
                        float4 hv = h0p[k];
                        PKDOT(P0, wX[0], k, hv); PKDOT(P1, wX[1], k, hv);
                    }
                    #pragma unroll
                    for (int k = 0; k < 7; ++k) {
                        float4 hv = h1p[k];
                        PKDOT(P0, wY[0], k, hv); PKDOT(P1, wY[1], k, hv);
                    }
                    float hv = cell(P0, P1, c[r]);
                    if ((lt & 3) == 0) h1s[pp ^ 1][r][u] = hv;
                }
                __builtin_amdgcn_s_setprio(0);
            }
        }
        __syncthreads();
    }

    // ---- epilogue: L1 computes h1(T-1). h0(511) in h0s[0]; h1(510) in h1s[0]. ----
    if (team == 1 && gl) {
        #pragma unroll
        for (int r = 0; r < R_; ++r) {
            const float4* h0p = (const float4*)(&h0s[0][r][s * HALFW]);
            const float4* h1p = (const float4*)(&h1s[0][r][s * HALFW]);
            v2f P0 = mk2(bias[0], 0.f), P1 = mk2(bias[1], 0.f);
            #pragma unroll
            for (int k = 0; k < 7; ++k) {
                float4 hv = h0p[k];
                PKDOT(P0, wX[0], k, hv); PKDOT(P1, wX[1], k, hv);
            }
            #pragma unroll
            for (int k = 0; k < 7; ++k) {
                float4 hv = h1p[k];
                PKDOT(P0, wY[0], k, hv); PKDOT(P1, wY[1], k, hv);
            }
            float hv = cell(P0, P1, c[r]);
            if ((lt & 3) == 0) h1s[1][r][u] = hv;    // h1(T-1)
        }
    }
    __syncthreads();

    // ---- FC epilogue: wave r reduces row r (4 rows, tid < 256) ----
    if (tid < R_ * FC_) {
        const int r = tid >> 6, f = tid & 63;
        const float* hf = h1s[1][r];
        float a = fc1_b[f];
        #pragma unroll
        for (int j = 0; j < H_; ++j) a += fc1_w[f * H_ + j] * hf[j];
        float v = fmaxf(a, 0.f) * fc2_w[f];
        #pragma unroll
        for (int off = 1; off < FC_; off <<= 1) v += __shfl_xor(v, off);
        if (f == 0) out[row0 + r] = v + fc2_b[0];
    }
}

extern "C" void kernel_launch(void* const* d_in, const int* in_sizes, int n_in,
                              void* d_out, int out_size, void* d_ws, size_t ws_size,
                              hipStream_t stream) {
    const float* x     = (const float*)d_in[0];
    const float* w_ih0 = (const float*)d_in[1];
    const float* w_hh0 = (const float*)d_in[2];
    const float* b_ih0 = (const float*)d_in[3];
    const float* b_hh0 = (const float*)d_in[4];
    const float* w_ih1 = (const float*)d_in[5];
    const float* w_hh1 = (const float*)d_in[6];
    const float* b_ih1 = (const float*)d_in[7];
    const float* b_hh1 = (const float*)d_in[8];
    const float* fc1_w = (const float*)d_in[9];
    const float* fc1_b = (const float*)d_in[10];
    const float* fc2_w = (const float*)d_in[11];
    const float* fc2_b = (const float*)d_in[12];
    float* out = (float*)d_out;

    dim3 grid(B_ / R_), block(512);
    hipLaunchKernelGGL(lstm_pipe4, grid, block, 0, stream,
                       x, w_ih0, w_hh0, b_ih0, b_hh0,
                       w_ih1, w_hh1, b_ih1, b_hh1,
                       fc1_w, fc1_b, fc2_w, fc2_b, out);
}